// Round 1
// baseline (1936.893 us; speedup 1.0000x reference)
//
#include <hip/hip_runtime.h>

#define N_NODES 20000
#define N_EDGES 640000
#define FDIM 64
#define NB 20
#define LN_EPS 1e-5f

__device__ __forceinline__ float silu_f(float x) {
    return x / (1.0f + __expf(-x));
}

// ---------------- Kernel A: node MLP  mn = silu(atom@W1+b1)@W2+b2 ----------------
__global__ __launch_bounds__(256) void node_mlp_kernel(
    const float* __restrict__ atom, const float* __restrict__ W1, const float* __restrict__ b1,
    const float* __restrict__ W2, const float* __restrict__ b2, float* __restrict__ mn)
{
    __shared__ float W1s[FDIM][FDIM];
    __shared__ float W2s[FDIM][FDIM];
    __shared__ float rowS[4][FDIM];
    __shared__ float hidS[4][FDIM];
    const int f = threadIdx.x, ty = threadIdx.y;
    const int tid = ty * 64 + f;
    for (int i = tid; i < FDIM * FDIM; i += 256) {
        ((float*)W1s)[i] = W1[i];
        ((float*)W2s)[i] = W2[i];
    }
    __syncthreads();
    const int n = blockIdx.x * 4 + ty;   // N_NODES % 4 == 0 -> always valid
    rowS[ty][f] = atom[n * FDIM + f];
    __syncthreads();
    float h = b1[f];
#pragma unroll
    for (int g = 0; g < FDIM; g += 4) {
        float4 a4 = *(const float4*)&rowS[ty][g];
        h += a4.x * W1s[g + 0][f] + a4.y * W1s[g + 1][f]
           + a4.z * W1s[g + 2][f] + a4.w * W1s[g + 3][f];
    }
    h = silu_f(h);
    hidS[ty][f] = h;
    __syncthreads();
    float o = b2[f];
#pragma unroll
    for (int g = 0; g < FDIM; g += 4) {
        float4 a4 = *(const float4*)&hidS[ty][g];
        o += a4.x * W2s[g + 0][f] + a4.y * W2s[g + 1][f]
           + a4.z * W2s[g + 2][f] + a4.w * W2s[g + 3][f];
    }
    mn[n * FDIM + f] = o;
}

// ---------------- Kernel B: per-edge pipeline ----------------
__global__ __launch_bounds__(256) void edge_kernel(
    const float* __restrict__ dist,   // [E,20]
    const float* __restrict__ dir,    // [E,3]
    const int* __restrict__ eidx,     // [2,E] int32
    const float* __restrict__ mn,     // [N,F]
    const float* __restrict__ We,     // [20,F]
    const float* __restrict__ Wq1a, const float* __restrict__ Wq1b,
    const float* __restrict__ Wq2a, const float* __restrict__ Wq2b,
    const float* __restrict__ forceN, // [N,3,F] original force_node
    float* __restrict__ atomAcc,      // [N,F]   (d_out atom region, pre-init atom_node)
    float* __restrict__ forceAcc)     // [N,3,F] (d_out force region, pre-init force_node)
{
    __shared__ float Aq1[FDIM][FDIM], Bq1[FDIM][FDIM];
    __shared__ float Aq2[FDIM][FDIM], Bq2[FDIM][FDIM];
    __shared__ float msgS[4][FDIM], h1S[4][FDIM], h2S[4][FDIM];
    const int f = threadIdx.x, ty = threadIdx.y;
    const int tid = ty * 64 + f;
    for (int i = tid; i < FDIM * FDIM; i += 256) {
        ((float*)Aq1)[i] = Wq1a[i];
        ((float*)Bq1)[i] = Wq1b[i];
        ((float*)Aq2)[i] = Wq2a[i];
        ((float*)Bq2)[i] = Wq2b[i];
    }
    __syncthreads();
    const int e = blockIdx.x * 4 + ty;  // N_EDGES % 4 == 0 -> always valid
    const int src = eidx[e];
    const int dst = eidx[N_EDGES + e];

    // me = dist_edge[e] @ We   (broadcast dist row via shuffles, We from L1)
    float dval = (f < NB) ? dist[e * NB + f] : 0.0f;
    float me = 0.0f;
#pragma unroll
    for (int b = 0; b < NB; ++b) {
        me += __shfl(dval, b, 64) * We[b * FDIM + f];
    }
    const float msg = me * mn[src * FDIM + f] * mn[dst * FDIM + f];
    atomicAdd(&atomAcc[src * FDIM + f], msg);

    msgS[ty][f] = msg;
    __syncthreads();
    float h1 = 0.0f, h2 = 0.0f;
#pragma unroll
    for (int g = 0; g < FDIM; g += 4) {
        float4 m4 = *(const float4*)&msgS[ty][g];
        h1 += m4.x * Aq1[g + 0][f] + m4.y * Aq1[g + 1][f]
            + m4.z * Aq1[g + 2][f] + m4.w * Aq1[g + 3][f];
        h2 += m4.x * Aq2[g + 0][f] + m4.y * Aq2[g + 1][f]
            + m4.z * Aq2[g + 2][f] + m4.w * Aq2[g + 3][f];
    }
    h1 = silu_f(h1);
    h2 = silu_f(h2);
    h1S[ty][f] = h1;
    h2S[ty][f] = h2;
    __syncthreads();
    float e1 = 0.0f, e2 = 0.0f;
#pragma unroll
    for (int g = 0; g < FDIM; g += 4) {
        float4 a4 = *(const float4*)&h1S[ty][g];
        float4 b4 = *(const float4*)&h2S[ty][g];
        e1 += a4.x * Bq1[g + 0][f] + a4.y * Bq1[g + 1][f]
            + a4.z * Bq1[g + 2][f] + a4.w * Bq1[g + 3][f];
        e2 += b4.x * Bq2[g + 0][f] + b4.y * Bq2[g + 1][f]
            + b4.z * Bq2[g + 2][f] + b4.w * Bq2[g + 3][f];
    }

    const float d0 = dir[e * 3 + 0];
    const float d1 = dir[e * 3 + 1];
    const float d2 = dir[e * 3 + 2];
    const float* fd = &forceN[(size_t)dst * 3 * FDIM];
    atomicAdd(&forceAcc[((size_t)src * 3 + 0) * FDIM + f], e1 * d0 + e2 * fd[0 * FDIM + f]);
    atomicAdd(&forceAcc[((size_t)src * 3 + 1) * FDIM + f], e1 * d1 + e2 * fd[1 * FDIM + f]);
    atomicAdd(&forceAcc[((size_t)src * 3 + 2) * FDIM + f], e1 * d2 + e2 * fd[2 * FDIM + f]);
}

// ---------------- Kernel C: finalize nodes (inv_update2 + LayerNorm) ----------------
__global__ __launch_bounds__(256) void node_final_kernel(
    const float* __restrict__ Wu, const float* __restrict__ gamma, const float* __restrict__ beta,
    float* __restrict__ atomAcc,   // [N,F]: atom_node + inv_update1 (in d_out)
    const float* __restrict__ forceOut) // [N,3,F]: final force (in d_out)
{
    __shared__ float Wus[FDIM][FDIM];
    __shared__ float fS[4][3][FDIM];
    const int f = threadIdx.x, ty = threadIdx.y;
    const int tid = ty * 64 + f;
    for (int i = tid; i < FDIM * FDIM; i += 256) ((float*)Wus)[i] = Wu[i];
    __syncthreads();
    const int n = blockIdx.x * 4 + ty;
    const float f0 = forceOut[((size_t)n * 3 + 0) * FDIM + f];
    const float f1 = forceOut[((size_t)n * 3 + 1) * FDIM + f];
    const float f2 = forceOut[((size_t)n * 3 + 2) * FDIM + f];
    fS[ty][0][f] = f0;
    fS[ty][1][f] = f1;
    fS[ty][2][f] = f2;
    __syncthreads();
    float r0 = 0.0f, r1 = 0.0f, r2 = 0.0f;
#pragma unroll
    for (int g = 0; g < FDIM; g += 4) {
        float4 a0 = *(const float4*)&fS[ty][0][g];
        float4 a1 = *(const float4*)&fS[ty][1][g];
        float4 a2 = *(const float4*)&fS[ty][2][g];
        r0 += a0.x * Wus[g + 0][f] + a0.y * Wus[g + 1][f]
            + a0.z * Wus[g + 2][f] + a0.w * Wus[g + 3][f];
        r1 += a1.x * Wus[g + 0][f] + a1.y * Wus[g + 1][f]
            + a1.z * Wus[g + 2][f] + a1.w * Wus[g + 3][f];
        r2 += a2.x * Wus[g + 0][f] + a2.y * Wus[g + 1][f]
            + a2.z * Wus[g + 2][f] + a2.w * Wus[g + 3][f];
    }
    float a = atomAcc[n * FDIM + f] + (f0 * r0 + f1 * r1 + f2 * r2);

    // LayerNorm over the 64 lanes (one wave per row)
    float s = a;
#pragma unroll
    for (int off = 32; off >= 1; off >>= 1) s += __shfl_xor(s, off, 64);
    const float mu = s * (1.0f / 64.0f);
    const float d = a - mu;
    float v = d * d;
#pragma unroll
    for (int off = 32; off >= 1; off >>= 1) v += __shfl_xor(v, off, 64);
    v *= (1.0f / 64.0f);
    atomAcc[n * FDIM + f] = d * rsqrtf(v + LN_EPS) * gamma[f] + beta[f];
}

extern "C" void kernel_launch(void* const* d_in, const int* in_sizes, int n_in,
                              void* d_out, int out_size, void* d_ws, size_t ws_size,
                              hipStream_t stream)
{
    const float* atom_node  = (const float*)d_in[0];
    const float* force_node = (const float*)d_in[1];
    const float* dir_edge   = (const float*)d_in[2];
    const float* dist_edge  = (const float*)d_in[3];
    const int*   edge_index = (const int*)d_in[4];
    const float* W1   = (const float*)d_in[5];
    const float* b1   = (const float*)d_in[6];
    const float* W2   = (const float*)d_in[7];
    const float* b2   = (const float*)d_in[8];
    const float* We   = (const float*)d_in[9];
    const float* Wq1a = (const float*)d_in[10];
    const float* Wq1b = (const float*)d_in[11];
    const float* Wq2a = (const float*)d_in[12];
    const float* Wq2b = (const float*)d_in[13];
    const float* Wu   = (const float*)d_in[14];
    const float* gamma = (const float*)d_in[15];
    const float* beta  = (const float*)d_in[16];

    float* atomOut  = (float*)d_out;                       // [N,F]
    float* forceOut = (float*)d_out + (size_t)N_NODES * FDIM; // [N,3,F]
    float* mn = (float*)d_ws;                              // [N,F] scratch

    // Initialize accumulators in d_out (deterministic: fully rewritten every call)
    hipMemcpyAsync(atomOut, atom_node, (size_t)N_NODES * FDIM * sizeof(float),
                   hipMemcpyDeviceToDevice, stream);
    hipMemcpyAsync(forceOut, force_node, (size_t)N_NODES * 3 * FDIM * sizeof(float),
                   hipMemcpyDeviceToDevice, stream);

    dim3 blk(64, 4);
    node_mlp_kernel<<<N_NODES / 4, blk, 0, stream>>>(atom_node, W1, b1, W2, b2, mn);
    edge_kernel<<<N_EDGES / 4, blk, 0, stream>>>(dist_edge, dir_edge, edge_index, mn, We,
                                                 Wq1a, Wq1b, Wq2a, Wq2b, force_node,
                                                 atomOut, forceOut);
    node_final_kernel<<<N_NODES / 4, blk, 0, stream>>>(Wu, gamma, beta, atomOut, forceOut);
}

// Round 2
// 1376.563 us; speedup vs baseline: 1.4071x; 1.4071x over previous
//
#include <hip/hip_runtime.h>

#define N_NODES 20000
#define N_EDGES 640000
#define FDIM 64
#define NB 20
#define LN_EPS 1e-5f
#define EPW 8          // edges per wave per iteration

__device__ __forceinline__ float silu_f(float x) {
    return x / (1.0f + __expf(-x));
}

// ---------------- Kernel A: node MLP  mn = silu(atom@W1+b1)@W2+b2 (persistent) ----------------
__global__ __launch_bounds__(256) void node_mlp_kernel(
    const float* __restrict__ atom, const float* __restrict__ W1, const float* __restrict__ b1,
    const float* __restrict__ W2, const float* __restrict__ b2, float* __restrict__ mn)
{
    __shared__ float W1s[FDIM][FDIM];
    __shared__ float W2s[FDIM][FDIM];
    __shared__ float rowS[4][FDIM];
    __shared__ float hidS[4][FDIM];
    const int f = threadIdx.x, ty = threadIdx.y;
    const int tid = ty * 64 + f;
    for (int i = tid; i < FDIM * FDIM; i += 256) {
        ((float*)W1s)[i] = W1[i];
        ((float*)W2s)[i] = W2[i];
    }
    __syncthreads();
    const float bb1 = b1[f], bb2 = b2[f];
    const int nw = gridDim.x * 4;
    for (int n = blockIdx.x * 4 + ty; n < N_NODES; n += nw) {
        rowS[ty][f] = atom[n * FDIM + f];          // wave-local, no barrier needed
        float h = bb1;
#pragma unroll
        for (int g = 0; g < FDIM; g += 4) {
            float4 a4 = *(const float4*)&rowS[ty][g];
            h += a4.x * W1s[g + 0][f] + a4.y * W1s[g + 1][f]
               + a4.z * W1s[g + 2][f] + a4.w * W1s[g + 3][f];
        }
        h = silu_f(h);
        hidS[ty][f] = h;
        float o = bb2;
#pragma unroll
        for (int g = 0; g < FDIM; g += 4) {
            float4 a4 = *(const float4*)&hidS[ty][g];
            o += a4.x * W2s[g + 0][f] + a4.y * W2s[g + 1][f]
               + a4.z * W2s[g + 2][f] + a4.w * W2s[g + 3][f];
        }
        mn[n * FDIM + f] = o;
    }
}

// ---------------- Kernel B: per-edge pipeline (persistent, 8 waves/block, EPW edges/wave) ------
__global__ __launch_bounds__(512) void edge_kernel(
    const float* __restrict__ dist,   // [E,20]
    const float* __restrict__ dir,    // [E,3]
    const int* __restrict__ eidx,     // [2,E] int32
    const float* __restrict__ mn,     // [N,F]
    const float* __restrict__ We,     // [20,F]
    const float* __restrict__ Wq1a, const float* __restrict__ Wq1b,
    const float* __restrict__ Wq2a, const float* __restrict__ Wq2b,
    const float* __restrict__ forceN, // [N,3,F] original force_node
    float* __restrict__ atomAcc,      // [N,F]
    float* __restrict__ forceAcc)     // [N,3,F]
{
    __shared__ float Aq1[FDIM][FDIM], Bq1[FDIM][FDIM];
    __shared__ float Aq2[FDIM][FDIM], Bq2[FDIM][FDIM];
    __shared__ float msgS[8][EPW][FDIM];
    __shared__ float h1S[8][EPW][FDIM];
    __shared__ float h2S[8][EPW][FDIM];
    const int f = threadIdx.x, ty = threadIdx.y;   // ty in 0..7
    const int tid = ty * 64 + f;
    for (int i = tid; i < FDIM * FDIM; i += 512) {
        ((float*)Aq1)[i] = Wq1a[i];
        ((float*)Bq1)[i] = Wq1b[i];
        ((float*)Aq2)[i] = Wq2a[i];
        ((float*)Bq2)[i] = Wq2b[i];
    }
    __syncthreads();   // only barrier in the kernel

    float we[NB];
#pragma unroll
    for (int b = 0; b < NB; ++b) we[b] = We[b * FDIM + f];

    const int ngroups = N_EDGES / EPW;
    const int stride = gridDim.x * 8;
    for (int grp = blockIdx.x * 8 + ty; grp < ngroups; grp += stride) {
        const int e0 = grp * EPW;
        int srcs[EPW], dsts[EPW];
#pragma unroll
        for (int j = 0; j < EPW; ++j) {
            srcs[j] = __builtin_amdgcn_readfirstlane(eidx[e0 + j]);
            dsts[j] = __builtin_amdgcn_readfirstlane(eidx[N_EDGES + e0 + j]);
        }
        // message = (dist@We) * mn[src] * mn[dst]; scatter to atomAcc; stage in wave-local LDS
#pragma unroll
        for (int j = 0; j < EPW; ++j) {
            float me = 0.0f;
#pragma unroll
            for (int b = 0; b < NB; ++b) me += dist[(e0 + j) * NB + b] * we[b];
            const float m = me * mn[srcs[j] * FDIM + f] * mn[dsts[j] * FDIM + f];
            atomicAdd(&atomAcc[srcs[j] * FDIM + f], m);
            msgS[ty][j][f] = m;
        }
        // h1 = silu(msg@Wq1a), h2 = silu(msg@Wq2a)  — weight rows amortized over EPW edges
        float h1[EPW], h2[EPW];
#pragma unroll
        for (int j = 0; j < EPW; ++j) { h1[j] = 0.0f; h2[j] = 0.0f; }
#pragma unroll
        for (int g = 0; g < FDIM; g += 4) {
            const float w1a = Aq1[g][f], w1b = Aq1[g + 1][f], w1c = Aq1[g + 2][f], w1d = Aq1[g + 3][f];
            const float w2a = Aq2[g][f], w2b = Aq2[g + 1][f], w2c = Aq2[g + 2][f], w2d = Aq2[g + 3][f];
#pragma unroll
            for (int j = 0; j < EPW; ++j) {
                float4 m4 = *(const float4*)&msgS[ty][j][g];
                h1[j] += m4.x * w1a + m4.y * w1b + m4.z * w1c + m4.w * w1d;
                h2[j] += m4.x * w2a + m4.y * w2b + m4.z * w2c + m4.w * w2d;
            }
        }
#pragma unroll
        for (int j = 0; j < EPW; ++j) {
            h1[j] = silu_f(h1[j]);
            h2[j] = silu_f(h2[j]);
            h1S[ty][j][f] = h1[j];
            h2S[ty][j][f] = h2[j];
        }
        // e1 = h1@Wq1b, e2 = h2@Wq2b
        float e1[EPW], e2[EPW];
#pragma unroll
        for (int j = 0; j < EPW; ++j) { e1[j] = 0.0f; e2[j] = 0.0f; }
#pragma unroll
        for (int g = 0; g < FDIM; g += 4) {
            const float v1a = Bq1[g][f], v1b = Bq1[g + 1][f], v1c = Bq1[g + 2][f], v1d = Bq1[g + 3][f];
            const float v2a = Bq2[g][f], v2b = Bq2[g + 1][f], v2c = Bq2[g + 2][f], v2d = Bq2[g + 3][f];
#pragma unroll
            for (int j = 0; j < EPW; ++j) {
                float4 a4 = *(const float4*)&h1S[ty][j][g];
                float4 b4 = *(const float4*)&h2S[ty][j][g];
                e1[j] += a4.x * v1a + a4.y * v1b + a4.z * v1c + a4.w * v1d;
                e2[j] += b4.x * v2a + b4.y * v2b + b4.z * v2c + b4.w * v2d;
            }
        }
        // equivariant scatter
#pragma unroll
        for (int j = 0; j < EPW; ++j) {
            const float d0 = dir[(e0 + j) * 3 + 0];
            const float d1 = dir[(e0 + j) * 3 + 1];
            const float d2 = dir[(e0 + j) * 3 + 2];
            const float* fd = forceN + (size_t)dsts[j] * 3 * FDIM;
            float* fa = forceAcc + (size_t)srcs[j] * 3 * FDIM;
            atomicAdd(&fa[0 * FDIM + f], e1[j] * d0 + e2[j] * fd[0 * FDIM + f]);
            atomicAdd(&fa[1 * FDIM + f], e1[j] * d1 + e2[j] * fd[1 * FDIM + f]);
            atomicAdd(&fa[2 * FDIM + f], e1[j] * d2 + e2[j] * fd[2 * FDIM + f]);
        }
    }
}

// ---------------- Kernel C: finalize nodes (inv_update2 + LayerNorm, persistent) ----------------
__global__ __launch_bounds__(256) void node_final_kernel(
    const float* __restrict__ Wu, const float* __restrict__ gamma, const float* __restrict__ beta,
    float* __restrict__ atomAcc,        // [N,F]
    const float* __restrict__ forceOut) // [N,3,F]
{
    __shared__ float Wus[FDIM][FDIM];
    __shared__ float fS[4][3][FDIM];
    const int f = threadIdx.x, ty = threadIdx.y;
    const int tid = ty * 64 + f;
    for (int i = tid; i < FDIM * FDIM; i += 256) ((float*)Wus)[i] = Wu[i];
    __syncthreads();
    const float gg = gamma[f], bb = beta[f];
    const int nw = gridDim.x * 4;
    for (int n = blockIdx.x * 4 + ty; n < N_NODES; n += nw) {
        const float f0 = forceOut[((size_t)n * 3 + 0) * FDIM + f];
        const float f1 = forceOut[((size_t)n * 3 + 1) * FDIM + f];
        const float f2 = forceOut[((size_t)n * 3 + 2) * FDIM + f];
        fS[ty][0][f] = f0;
        fS[ty][1][f] = f1;
        fS[ty][2][f] = f2;
        float r0 = 0.0f, r1 = 0.0f, r2 = 0.0f;
#pragma unroll
        for (int g = 0; g < FDIM; g += 4) {
            float4 a0 = *(const float4*)&fS[ty][0][g];
            float4 a1 = *(const float4*)&fS[ty][1][g];
            float4 a2 = *(const float4*)&fS[ty][2][g];
            const float wa = Wus[g + 0][f], wb = Wus[g + 1][f], wc = Wus[g + 2][f], wd = Wus[g + 3][f];
            r0 += a0.x * wa + a0.y * wb + a0.z * wc + a0.w * wd;
            r1 += a1.x * wa + a1.y * wb + a1.z * wc + a1.w * wd;
            r2 += a2.x * wa + a2.y * wb + a2.z * wc + a2.w * wd;
        }
        float a = atomAcc[n * FDIM + f] + (f0 * r0 + f1 * r1 + f2 * r2);
        float s = a;
#pragma unroll
        for (int off = 32; off >= 1; off >>= 1) s += __shfl_xor(s, off, 64);
        const float mu = s * (1.0f / 64.0f);
        const float d = a - mu;
        float v = d * d;
#pragma unroll
        for (int off = 32; off >= 1; off >>= 1) v += __shfl_xor(v, off, 64);
        v *= (1.0f / 64.0f);
        atomAcc[n * FDIM + f] = d * rsqrtf(v + LN_EPS) * gg + bb;
    }
}

extern "C" void kernel_launch(void* const* d_in, const int* in_sizes, int n_in,
                              void* d_out, int out_size, void* d_ws, size_t ws_size,
                              hipStream_t stream)
{
    const float* atom_node  = (const float*)d_in[0];
    const float* force_node = (const float*)d_in[1];
    const float* dir_edge   = (const float*)d_in[2];
    const float* dist_edge  = (const float*)d_in[3];
    const int*   edge_index = (const int*)d_in[4];
    const float* W1   = (const float*)d_in[5];
    const float* b1   = (const float*)d_in[6];
    const float* W2   = (const float*)d_in[7];
    const float* b2   = (const float*)d_in[8];
    const float* We   = (const float*)d_in[9];
    const float* Wq1a = (const float*)d_in[10];
    const float* Wq1b = (const float*)d_in[11];
    const float* Wq2a = (const float*)d_in[12];
    const float* Wq2b = (const float*)d_in[13];
    const float* Wu   = (const float*)d_in[14];
    const float* gamma = (const float*)d_in[15];
    const float* beta  = (const float*)d_in[16];

    float* atomOut  = (float*)d_out;                          // [N,F]
    float* forceOut = (float*)d_out + (size_t)N_NODES * FDIM; // [N,3,F]
    float* mn = (float*)d_ws;                                 // [N,F] scratch

    hipMemcpyAsync(atomOut, atom_node, (size_t)N_NODES * FDIM * sizeof(float),
                   hipMemcpyDeviceToDevice, stream);
    hipMemcpyAsync(forceOut, force_node, (size_t)N_NODES * 3 * FDIM * sizeof(float),
                   hipMemcpyDeviceToDevice, stream);

    dim3 blk4(64, 4);
    dim3 blk8(64, 8);
    node_mlp_kernel<<<512, blk4, 0, stream>>>(atom_node, W1, b1, W2, b2, mn);
    edge_kernel<<<256, blk8, 0, stream>>>(dist_edge, dir_edge, edge_index, mn, We,
                                          Wq1a, Wq1b, Wq2a, Wq2b, force_node,
                                          atomOut, forceOut);
    node_final_kernel<<<512, blk4, 0, stream>>>(Wu, gamma, beta, atomOut, forceOut);
}